// Round 2
// baseline (10258.976 us; speedup 1.0000x reference)
//
#include <hip/hip_runtime.h>
#include <hip/hip_bf16.h>
#include <math.h>

#define TT 64
#define NN 8
#define BB 128
#define DD 128
#define HH 512
#define SS 64
#define KK 16
#define AA 16
#define NB 1024
#define H3 (3*HH)       /* 1536 */

__device__ __forceinline__ float sigm(float x){ return 1.0f/(1.0f+expf(-x)); }

// ---------------- done-layout detection + mask expansion ----------------
// flag: 0 = int32, 1 = uint8/bool, 2 = float32
__global__ __launch_bounds__(256) void k_detect(const unsigned char* __restrict__ raw,
                                                int* __restrict__ flag)
{
  __shared__ int cA, cB;
  if (threadIdx.x == 0){ cA = 0; cB = 0; }
  __syncthreads();
  int a = 0, b = 0;
  for (int i = threadIdx.x; i < TT*NB; i += 256){   // first 64KB: safe under all layouts
    unsigned char v = raw[i];
    if (v > 1) a++;
    if ((i & 3) != 0 && v != 0) b++;
  }
  atomicAdd(&cA, a); atomicAdd(&cB, b);
  __syncthreads();
  if (threadIdx.x == 0) *flag = (cB == 0) ? 0 : (cA == 0 ? 1 : 2);
}

__global__ __launch_bounds__(256) void k_mask(const unsigned char* __restrict__ raw,
                                              const int* __restrict__ flag,
                                              float* __restrict__ mask)
{
  int i = blockIdx.x*256 + threadIdx.x;
  if (i >= TT*NB) return;
  int f = *flag;
  int v;
  if (f == 1)      v = (int)raw[i];
  else if (f == 0) v = ((const int*)raw)[i];
  else             v = (((const float*)raw)[i] != 0.0f);
  mask[i] = v ? 0.f : 1.f;   // 0 => reset carry
}

// ---------------- small setup kernels ----------------

// e = tanh(relu(W_e1 + b_e1) @ W_e2 + b_e2)   (eye(K)@W_e1 == W_e1)
__global__ __launch_bounds__(256) void k_e(const float* __restrict__ W_e1, const float* __restrict__ b_e1,
                                           const float* __restrict__ W_e2, const float* __restrict__ b_e2,
                                           float* __restrict__ e_out)
{
  __shared__ float r1[KK*SS];
  int tid = threadIdx.x;
  for (int i=0;i<4;++i){ int l = tid + i*256; float v = W_e1[l] + b_e1[l & 63]; r1[l] = v > 0.f ? v : 0.f; }
  __syncthreads();
  for (int i=0;i<4;++i){
    int l = tid + i*256; int k = l >> 6, s = l & 63;
    float acc = b_e2[s];
    #pragma unroll 8
    for (int sp=0; sp<64; ++sp) acc += r1[k*64+sp] * W_e2[sp*64 + s];
    e_out[l] = tanhf(acc);
  }
}

// w1[k,h,a] = e[k,:]@W_w1[:,h*A+a] + b_w1 ;  b1[k,a] = e[k,:]@W_b1[:,a] + b_b1
__global__ __launch_bounds__(256) void k_w1b1(const float* __restrict__ e, const float* __restrict__ W_w1,
                                              const float* __restrict__ b_w1, const float* __restrict__ W_b1,
                                              const float* __restrict__ b_b1, float* __restrict__ w1,
                                              float* __restrict__ b1)
{
  __shared__ float es[KK*SS];
  int tid = threadIdx.x;
  for (int i=0;i<4;++i) es[tid + i*256] = e[tid + i*256];
  __syncthreads();
  for (int i=0;i<4;++i){
    int l = blockIdx.x*1024 + tid + i*256;         // < 131072
    int k = l >> 13, m = l & 8191;                  // m = h*16+a
    float acc = b_w1[m];
    #pragma unroll 8
    for (int s=0;s<64;++s) acc += es[k*64+s] * W_w1[(size_t)s*8192 + m];
    w1[l] = acc;
  }
  if (blockIdx.x == 0){
    int k = tid >> 4, a = tid & 15;
    float acc = b_b1[a];
    #pragma unroll 8
    for (int s=0;s<64;++s) acc += es[k*64+s] * W_b1[s*16 + a];
    b1[tid] = acc;
  }
}

// subtask_embed output: broadcast e over (T,B) -> (T,B,K,S)
__global__ __launch_bounds__(256) void k_se(const float* __restrict__ e, float* __restrict__ outse)
{
  __shared__ float4 es[256];
  es[threadIdx.x] = ((const float4*)e)[threadIdx.x];
  __syncthreads();
  const int total4 = TT*BB*KK*SS/4;   // 2097152
  for (int i = blockIdx.x*256 + threadIdx.x; i < total4; i += gridDim.x*256)
    ((float4*)outse)[i] = es[i & 255];
}

__global__ void k_copy(const float* __restrict__ src, float* __restrict__ dst, int n4)
{
  int i = blockIdx.x*blockDim.x + threadIdx.x;
  if (i < n4) ((float4*)dst)[i] = ((const float4*)src)[i];
}

// ---------------- generic tiled f32 GEMM: C = act(A@W + bias) ----------------
template<int RELU>
__global__ __launch_bounds__(256) void gemm_bias_act(
    const float* __restrict__ A, const float* __restrict__ W,
    const float* __restrict__ bias, float* __restrict__ C,
    int M, int Kd, int Nc)
{
  __shared__ float As[16][72];
  __shared__ float Bs[16][72];
  int tid = threadIdx.x;
  int tx = tid & 15, ty = tid >> 4;
  int rowBase = blockIdx.y * 64;
  int colBase = blockIdx.x * 64;
  float acc[4][4] = {};
  for (int k0 = 0; k0 < Kd; k0 += 16){
    {
      int r  = tid >> 2;
      int kb = (tid & 3) * 4;
      float4 v = *(const float4*)&A[(size_t)(rowBase + r)*Kd + k0 + kb];
      As[kb+0][r]=v.x; As[kb+1][r]=v.y; As[kb+2][r]=v.z; As[kb+3][r]=v.w;
    }
    #pragma unroll
    for (int i=0;i<4;++i){
      int l = i*256 + tid;
      int kk = l >> 6, c = l & 63;
      Bs[kk][c] = W[(size_t)(k0+kk)*Nc + colBase + c];
    }
    __syncthreads();
    #pragma unroll
    for (int kk=0;kk<16;++kk){
      float4 a4 = *(const float4*)&As[kk][ty*4];
      float4 b4 = *(const float4*)&Bs[kk][tx*4];
      float av[4]={a4.x,a4.y,a4.z,a4.w}, bv[4]={b4.x,b4.y,b4.z,b4.w};
      #pragma unroll
      for (int i=0;i<4;++i)
        #pragma unroll
        for (int j=0;j<4;++j) acc[i][j] += av[i]*bv[j];
    }
    __syncthreads();
  }
  int c0 = colBase + tx*4;
  float4 bv4 = *(const float4*)&bias[c0];
  float bb[4]={bv4.x,bv4.y,bv4.z,bv4.w};
  for (int i=0;i<4;++i){
    int r = rowBase + ty*4 + i;
    float o[4];
    #pragma unroll
    for (int j=0;j<4;++j){ float v = acc[i][j] + bb[j]; if (RELU) v = v>0.f?v:0.f; o[j]=v; }
    *(float4*)&C[(size_t)r*Nc + c0] = make_float4(o[0],o[1],o[2],o[3]);
  }
}

// ---------------- fused GRU step ----------------
__global__ __launch_bounds__(256) void gru_step(
    const float* __restrict__ hprev, const float* __restrict__ gi,
    const float* __restrict__ Wh, const float* __restrict__ bhn,
    const float* __restrict__ mask_t, float* __restrict__ hout)
{
  __shared__ float hs[16][17];
  __shared__ float Wsh[3][16][68];
  __shared__ float dms[16];
  int tid = threadIdx.x;
  int tx = tid & 15, ty = tid >> 4;
  int colBase = blockIdx.x * 64;
  int rowBase = blockIdx.y * 16;
  if (tid < 16) dms[tid] = mask_t[rowBase + tid];
  __syncthreads();
  float accR[4]={0,0,0,0}, accZ[4]={0,0,0,0}, accN[4]={0,0,0,0};
  for (int k0=0;k0<HH;k0+=16){
    {
      int row = tid >> 4, kk = tid & 15;
      hs[row][kk] = hprev[(size_t)(rowBase+row)*HH + k0 + kk] * dms[row];
    }
    #pragma unroll
    for (int g=0; g<3; ++g){
      int cb = g*HH + colBase;
      #pragma unroll
      for (int i=0;i<4;++i){
        int l = i*256 + tid;
        int kk = l >> 6, c = l & 63;
        Wsh[g][kk][c] = Wh[(size_t)(k0+kk)*H3 + cb + c];
      }
    }
    __syncthreads();
    #pragma unroll
    for (int kk=0;kk<16;++kk){
      float a = hs[ty][kk];
      float4 wr = *(const float4*)&Wsh[0][kk][tx*4];
      float4 wz = *(const float4*)&Wsh[1][kk][tx*4];
      float4 wn = *(const float4*)&Wsh[2][kk][tx*4];
      accR[0]+=a*wr.x; accR[1]+=a*wr.y; accR[2]+=a*wr.z; accR[3]+=a*wr.w;
      accZ[0]+=a*wz.x; accZ[1]+=a*wz.y; accZ[2]+=a*wz.z; accZ[3]+=a*wz.w;
      accN[0]+=a*wn.x; accN[1]+=a*wn.y; accN[2]+=a*wn.z; accN[3]+=a*wn.w;
    }
    __syncthreads();
  }
  int jrow = rowBase + ty;
  int c0 = colBase + tx*4;
  size_t gb = (size_t)jrow*H3 + c0;
  float4 gr = *(const float4*)&gi[gb];
  float4 gz = *(const float4*)&gi[gb + HH];
  float4 gn = *(const float4*)&gi[gb + 2*HH];
  float4 bn4 = *(const float4*)&bhn[c0];
  float dm = dms[ty];
  float4 hp4 = *(const float4*)&hprev[(size_t)jrow*HH + c0];
  float hpv[4]={hp4.x*dm,hp4.y*dm,hp4.z*dm,hp4.w*dm};
  float grv[4]={gr.x,gr.y,gr.z,gr.w};
  float gzv[4]={gz.x,gz.y,gz.z,gz.w};
  float gnv[4]={gn.x,gn.y,gn.z,gn.w};
  float bnv[4]={bn4.x,bn4.y,bn4.z,bn4.w};
  float o[4];
  #pragma unroll
  for (int j=0;j<4;++j){
    float rg = sigm(grv[j] + accR[j]);
    float zg = sigm(gzv[j] + accZ[j]);
    float ng = tanhf(gnv[j] + rg*(accN[j] + bnv[j]));
    o[j] = (1.f - zg)*ng + zg*hpv[j];
  }
  *(float4*)&hout[(size_t)jrow*HH + c0] = make_float4(o[0],o[1],o[2],o[3]);
}

// ---------------- logits + first-max argmax (chunked: t = t0 + local) ----------------
__global__ __launch_bounds__(256) void k_logits(const float* __restrict__ ae2,
    const float* __restrict__ e, float* __restrict__ out_logits, int* __restrict__ argk, int t0)
{
  __shared__ float es[KK*SS];
  int tid = threadIdx.x;
  for (int i=0;i<4;++i) es[tid + i*256] = e[tid + i*256];
  __syncthreads();
  int g = blockIdx.x*256 + tid;       // local: lt*1024 + j
  int t = t0 + (g >> 10), j = g & 1023;
  const float* arow = &ae2[(size_t)g * SS];
  float a[SS];
  #pragma unroll
  for (int i=0;i<16;++i){ float4 v = ((const float4*)arow)[i]; a[4*i]=v.x; a[4*i+1]=v.y; a[4*i+2]=v.z; a[4*i+3]=v.w; }
  float lg[KK];
  float best = -INFINITY; int bk = 0;
  for (int k=0;k<KK;++k){
    float s2 = 0.f;
    #pragma unroll 8
    for (int s=0;s<SS;++s) s2 += a[s]*es[k*SS+s];
    lg[k] = s2;
    if (s2 > best){ best = s2; bk = k; }
  }
  int n = j >> 7, b = j & 127;
  size_t ob = ((size_t)((t*BB + b)*NN + n)) * KK;
  #pragma unroll
  for (int k4=0;k4<4;++k4)
    *(float4*)&out_logits[ob + k4*4] = make_float4(lg[k4*4],lg[k4*4+1],lg[k4*4+2],lg[k4*4+3]);
  argk[(t*BB + b)*NN + n] = bk;       // (b,n)-major within t == index t*1024 + b*8 + n
}

// ---------------- q selection (chunked): q[bj] = y2[bj]@w1[k*] + b1[k*] ----------------
__global__ __launch_bounds__(64) void k_qsel(const float* __restrict__ y2,
    const float* __restrict__ w1, const float* __restrict__ b1,
    const int* __restrict__ argk, float* __restrict__ outq)
{
  __shared__ float yr[HH];
  __shared__ float part[64];
  int bj = blockIdx.x;
  int tid = threadIdx.x;
  const float4* row4 = (const float4*)&y2[(size_t)bj*HH];
  ((float4*)yr)[tid]    = row4[tid];
  ((float4*)yr)[tid+64] = row4[tid+64];
  __syncthreads();
  int k = argk[bj];
  int a = tid & 15, q4 = tid >> 4;
  const float* wp = &w1[(size_t)k*HH*AA + a];
  float s = 0.f;
  int h0 = q4*128;
  #pragma unroll 8
  for (int h=h0; h<h0+128; ++h) s += yr[h]*wp[(size_t)h*AA];
  part[tid] = s;
  __syncthreads();
  if (q4 == 0){
    float v = part[a] + part[a+16] + part[a+32] + part[a+48] + b1[k*AA + a];
    outq[(size_t)bj*AA + a] = v;
  }
}

// ---------------- orchestration ----------------
extern "C" void kernel_launch(void* const* d_in, const int* in_sizes, int n_in,
                              void* d_out, int out_size, void* d_ws, size_t ws_size,
                              hipStream_t stream)
{
  (void)in_sizes; (void)n_in; (void)out_size;
  const float* h1     = (const float*)d_in[0];
  const float* h2     = (const float*)d_in[1];
  const float* obs    = (const float*)d_in[2];
  const unsigned char* done_raw = (const unsigned char*)d_in[3];
  const float* W_embed=(const float*)d_in[4];  const float* b_embed=(const float*)d_in[5];
  const float* Wi1    =(const float*)d_in[6];  const float* bi1    =(const float*)d_in[7];
  const float* Wh1    =(const float*)d_in[8];  const float* bhn1   =(const float*)d_in[9];
  const float* W_sub  =(const float*)d_in[10]; const float* b_sub  =(const float*)d_in[11];
  const float* W_e1   =(const float*)d_in[12]; const float* b_e1   =(const float*)d_in[13];
  const float* W_e2   =(const float*)d_in[14]; const float* b_e2   =(const float*)d_in[15];
  const float* W_pol  =(const float*)d_in[16]; const float* b_pol  =(const float*)d_in[17];
  const float* Wi2    =(const float*)d_in[18]; const float* bi2    =(const float*)d_in[19];
  const float* Wh2    =(const float*)d_in[20]; const float* bhn2   =(const float*)d_in[21];
  const float* W_w1   =(const float*)d_in[22]; const float* b_w1   =(const float*)d_in[23];
  const float* W_b1   =(const float*)d_in[24]; const float* b_b1   =(const float*)d_in[25];

  float* out    = (float*)d_out;
  float* outHT1 = out;
  float* outHT2 = out + (size_t)NB*HH;
  float* outQ   = out + 2ull*NB*HH;
  float* outLG  = outQ + (size_t)TT*NB*AA;
  float* outSE  = outLG + (size_t)TT*BB*NN*KK;

  // ---- adaptive chunk size from ws_size ----
  const size_t fixed_f = (size_t)NB*HH /*h_last*/ + (size_t)TT*NB /*mask*/ + 1024 /*e*/
                       + (size_t)KK*HH*AA /*w1*/ + 256 /*b1*/ + (size_t)TT*NB /*argk*/ + 256 /*flag*/;
  const size_t per_t_f = (size_t)NB*(HH + H3 + SS);   // buf + gbuf + ae2buf per timestep
  int CH = 64;
  while (CH > 1 && (fixed_f + per_t_f*(size_t)CH)*4 > ws_size) CH >>= 1;

  float* buf    = (float*)d_ws;                       // ae/y chunk: CH*NB*HH
  float* gbuf   = buf  + (size_t)CH*NB*HH;            // gi chunk:   CH*NB*H3
  float* ae2buf = gbuf + (size_t)CH*NB*H3;            // ae2 chunk:  CH*NB*SS
  float* h_last = ae2buf + (size_t)CH*NB*SS;          // NB*HH
  float* mask   = h_last + (size_t)NB*HH;             // TT*NB
  float* ws_e   = mask + (size_t)TT*NB;               // 1024
  float* ws_w1  = ws_e + 1024;                        // 131072
  float* ws_b1  = ws_w1 + (size_t)KK*HH*AA;           // 256
  int*   ws_argk= (int*)(ws_b1 + 256);                // TT*NB ints
  int*   ws_flag= (int*)(ws_argk + (size_t)TT*NB);

  // phase 0: done-mask + subtask-embedding constants + broadcast output
  k_detect<<<1,256,0,stream>>>(done_raw, ws_flag);
  k_mask<<<TT*NB/256,256,0,stream>>>(done_raw, ws_flag, mask);
  k_e<<<1,256,0,stream>>>(W_e1,b_e1,W_e2,b_e2,ws_e);
  k_w1b1<<<128,256,0,stream>>>(ws_e,W_w1,b_w1,W_b1,b_b1,ws_w1,ws_b1);
  k_se<<<2048,256,0,stream>>>(ws_e,outSE);

  dim3 thr(256);
  const int NCH = TT / CH;
  for (int br = 0; br < 2; ++br){
    const float* Wemb = br ? W_pol : W_embed;
    const float* bemb = br ? b_pol : b_embed;
    const float* Wi   = br ? Wi2   : Wi1;
    const float* bi   = br ? bi2   : bi1;
    const float* Wh   = br ? Wh2   : Wh1;
    const float* bhn  = br ? bhn2  : bhn1;
    const float* h0   = br ? h2    : h1;

    k_copy<<<512,256,0,stream>>>(h0, h_last, NB*HH/4);
    for (int c = 0; c < NCH; ++c){
      int t0 = c * CH;
      // ae/sp chunk: relu(obs@W + b) into buf
      gemm_bias_act<1><<<dim3(HH/64, CH*NB/64),thr,0,stream>>>(obs + (size_t)t0*NB*DD, Wemb, bemb, buf, CH*NB, DD, HH);
      // gi chunk
      gemm_bias_act<0><<<dim3(H3/64, CH*NB/64),thr,0,stream>>>(buf, Wi, bi, gbuf, CH*NB, HH, H3);
      // scan (overwrites buf slots with y)
      for (int lt = 0; lt < CH; ++lt){
        const float* hp = (lt == 0) ? h_last : (buf + (size_t)(lt-1)*NB*HH);
        gru_step<<<dim3(HH/64, NB/16),thr,0,stream>>>(hp, gbuf + (size_t)lt*NB*H3, Wh, bhn,
                                                      mask + (size_t)(t0+lt)*NB, buf + (size_t)lt*NB*HH);
      }
      k_copy<<<512,256,0,stream>>>(buf + (size_t)(CH-1)*NB*HH, h_last, NB*HH/4);
      if (br == 0){
        gemm_bias_act<0><<<dim3(SS/64, CH*NB/64),thr,0,stream>>>(buf, W_sub, b_sub, ae2buf, CH*NB, HH, SS);
        k_logits<<<CH*NB/256,256,0,stream>>>(ae2buf, ws_e, outLG, ws_argk, t0);
      } else {
        k_qsel<<<CH*NB,64,0,stream>>>(buf, ws_w1, ws_b1, ws_argk + (size_t)t0*NB, outQ + (size_t)t0*NB*AA);
      }
    }
    k_copy<<<512,256,0,stream>>>(h_last, br ? outHT2 : outHT1, NB*HH/4);
  }
}